// Round 7
// baseline (166.913 us; speedup 1.0000x reference)
//
#include <hip/hip_runtime.h>
#include <math.h>

// knnLoss: B=4, N=8192, k=3 via MFMA. d^2(s,t) embedded as a K=13 bf16
// hi/lo-split dot product: one mfma_f32_16x16x32_bf16 = 256 pairwise d^2.
// A slots (per source): [-2sx_h,-2sx_h,-2sx_l, -2sy_h,-2sy_h,-2sy_l,
//                        -2sz_h,-2sz_h | -2sz_l, s2_h, s2_l, 1, 1, 0,0,0 | 0...]
// B slots (per target): [tx_h,tx_l,tx_h, ty_h,ty_l,ty_h, tz_h,tz_l |
//                        tz_h, 1, 1, t2_h, t2_l, 0,0,0 | don't-care]
// K slots 16-31 of A are zero => B upper quads are don't-care (lanes 32-63
// alias lanes 0-31's fragment load; no masking needed).
#define BATCH 4
#define NPTS 8192
#define TILES 512           // 16-target tiles per batch

typedef __attribute__((ext_vector_type(8))) short short8;
typedef __attribute__((ext_vector_type(4))) float floatx4;

__device__ __forceinline__ unsigned short bf16hi(float v) {
    unsigned u = __float_as_uint(v);
    return (unsigned short)((u + 0x7FFFu + ((u >> 16) & 1u)) >> 16);
}
__device__ __forceinline__ float bf16f(unsigned short h) {
    return __uint_as_float(((unsigned)h) << 16);
}

// Branchless insert into sorted ascending triple; 4 ops via med3.
__device__ __forceinline__ void insert3(float d, float& a0, float& a1, float& a2) {
    float h = fmaxf(a1, d);
    float m = __builtin_amdgcn_fmed3f(a0, a1, d);
    a2 = fminf(a2, h);
    a1 = m;
    a0 = fminf(a0, d);
}

// Merge two sorted triples -> sorted 3 smallest of union (into b). 6 ops.
__device__ __forceinline__ void merge33(float a0, float a1, float a2,
                                        float& b0, float& b1, float& b2) {
    float s0 = fminf(a0, b0);
    float h  = fmaxf(a0, b0);
    float m  = fminf(a1, b1);
    float mm = fminf(a2, b2);
    b1 = fminf(h, m);
    b2 = __builtin_amdgcn_fmed3f(h, m, mm);
    b0 = s0;
}

// Pack B fragments: entry (batch,tile,lane32) -> 8 bf16 of B[k=q*8+j][n],
// q=lane32>>4, n=lane32&15. 16 B per entry, 512 B per tile, 1 MB total.
__global__ __launch_bounds__(256) void knn_prep(const float* __restrict__ tgt,
                                                short8* __restrict__ packed,
                                                float* __restrict__ hdr) {
    int gid = blockIdx.x * 256 + threadIdx.x;   // 0..65535
    if (gid < 16) hdr[gid] = 0.0f;              // zero acc/cnt/ticket header
    int lane = gid & 31;
    int bt = gid >> 5;                          // batch*512 + tile
    int n = lane & 15;
    int q = lane >> 4;                          // 0 or 1
    int batch = bt >> 9, tile = bt & 511;
    const float* tp = tgt + ((size_t)batch * NPTS + tile * 16 + n) * 3;
    float x = tp[0], y = tp[1], z = tp[2];
    float t2 = x * x + y * y + z * z;
    if (!(x != 0.f || y != 0.f || z != 0.f)) t2 = 3.0e38f;  // invalid-target sentinel
    unsigned short xh = bf16hi(x),  xl = bf16hi(x - bf16f(xh));
    unsigned short yh = bf16hi(y),  yl = bf16hi(y - bf16f(yh));
    unsigned short zh = bf16hi(z),  zl = bf16hi(z - bf16f(zh));
    unsigned short th = bf16hi(t2), tl = bf16hi(t2 - bf16f(th));
    const short one = (short)0x3F80;  // bf16(1.0)
    short8 v;
    if (q == 0)
        v = (short8){(short)xh, (short)xl, (short)xh, (short)yh,
                     (short)yl, (short)yh, (short)zh, (short)zl};
    else
        v = (short8){(short)zh, one, one, (short)th, (short)tl, 0, 0, 0};
    packed[(size_t)bt * 32 + lane] = v;
}

// grid (128,1,4), 256 threads = 4 waves; each wave: 16 sources x all 8192
// targets of its batch. 512 blocks = 2/CU.
__global__ __launch_bounds__(256) void knn_main(const float* __restrict__ src,
                                                const short8* __restrict__ packed,
                                                float* __restrict__ acc,
                                                float* __restrict__ cnt,
                                                unsigned* __restrict__ ticket,
                                                float* __restrict__ out) {
    const int tid = threadIdx.x;
    const int wave = tid >> 6, lane = tid & 63;
    const int b = blockIdx.z;
    const int sg = blockIdx.x * 4 + wave;   // 16-source group, 0..511
    const int m = lane & 15, q = lane >> 4;

    // A fragment for source m of this group (k = q*8+j).
    const float* sp = src + ((size_t)b * NPTS + sg * 16 + m) * 3;
    float sx = sp[0], sy = sp[1], sz = sp[2];
    float s2 = sx * sx + sy * sy + sz * sz;
    float mx = -2.f * sx, my = -2.f * sy, mz = -2.f * sz;
    unsigned short xh = bf16hi(mx), xl = bf16hi(mx - bf16f(xh));
    unsigned short yh = bf16hi(my), yl = bf16hi(my - bf16f(yh));
    unsigned short zh = bf16hi(mz), zl = bf16hi(mz - bf16f(zh));
    unsigned short sh = bf16hi(s2), sl = bf16hi(s2 - bf16f(sh));
    const short one = (short)0x3F80;
    short8 afrag = (short8){0, 0, 0, 0, 0, 0, 0, 0};
    if (q == 0)
        afrag = (short8){(short)xh, (short)xh, (short)xl, (short)yh,
                         (short)yh, (short)yl, (short)zh, (short)zh};
    else if (q == 1)
        afrag = (short8){(short)zl, (short)sh, (short)sl, one, one, 0, 0, 0};
    // q = 2,3: zero (this is what makes B's upper quads don't-care).

    // Per-lane triples for C rows q*4+j (col = lane&15), ascending d^2.
    float t0[4], t1[4], t2[4];
    #pragma unroll
    for (int j = 0; j < 4; ++j) { t0[j] = t1[j] = t2[j] = 3e38f; }

    // Lanes 32-63 alias lanes 0-31's fragment (their A is zero).
    const short8* bb = packed + (size_t)b * TILES * 32 + (lane & 31);

    #pragma unroll 4
    for (int tile = 0; tile < TILES; ++tile) {
        short8 bfrag = bb[(size_t)tile * 32];   // coalesced 16 B/lane
        floatx4 c = {0.f, 0.f, 0.f, 0.f};
        c = __builtin_amdgcn_mfma_f32_16x16x32_bf16(afrag, bfrag, c, 0, 0, 0);
        insert3(c[0], t0[0], t1[0], t2[0]);
        insert3(c[1], t0[1], t1[1], t2[1]);
        insert3(c[2], t0[2], t1[2], t2[2]);
        insert3(c[3], t0[3], t1[3], t2[3]);
    }

    // Butterfly-merge the 16 column-lanes of each quad (masks 1,2,4,8 stay
    // within the quad); afterwards every lane holds full top-3 per row.
    #pragma unroll
    for (int mask = 1; mask <= 8; mask <<= 1) {
        #pragma unroll
        for (int j = 0; j < 4; ++j) {
            float b0 = __shfl_xor(t0[j], mask);
            float b1 = __shfl_xor(t1[j], mask);
            float b2 = __shfl_xor(t2[j], mask);
            merge33(b0, b1, b2, t0[j], t1[j], t2[j]);
        }
    }

    // Lane (q, c<4) finalizes row q*4+c: sqrt + source-validity mask.
    int cc = lane & 15;
    float dsum = 0.f, dcnt = 0.f;
    if (cc < 4) {
        float m0 = t0[0], m1 = t1[0], m2 = t2[0];
        if (cc == 1) { m0 = t0[1]; m1 = t1[1]; m2 = t2[1]; }
        if (cc == 2) { m0 = t0[2]; m1 = t1[2]; m2 = t2[2]; }
        if (cc == 3) { m0 = t0[3]; m1 = t1[3]; m2 = t2[3]; }
        int row = q * 4 + cc;
        const float* vp = src + ((size_t)b * NPTS + sg * 16 + row) * 3;
        float vx = vp[0], vy = vp[1], vz = vp[2];
        if (vx != 0.f || vy != 0.f || vz != 0.f) {
            dsum = sqrtf(fmaxf(m0, 0.f)) + sqrtf(fmaxf(m1, 0.f)) +
                   sqrtf(fmaxf(m2, 0.f));
            dcnt = 1.f;
        }
    }
    for (int off = 32; off >= 1; off >>= 1) {
        dsum += __shfl_down(dsum, off);
        dcnt += __shfl_down(dcnt, off);
    }
    __shared__ float rs[4], rc[4];
    if (lane == 0) { rs[wave] = dsum; rc[wave] = dcnt; }
    __syncthreads();
    if (tid == 0) {
        atomicAdd(&acc[b], rs[0] + rs[1] + rs[2] + rs[3]);
        atomicAdd(&cnt[b], rc[0] + rc[1] + rc[2] + rc[3]);
        __threadfence();
        unsigned t = atomicAdd(ticket, 1u);
        unsigned total = gridDim.x * gridDim.y * gridDim.z;
        if (t == total - 1) {
            float loss = 0.f;
            #pragma unroll
            for (int bb2 = 0; bb2 < BATCH; ++bb2) {
                float as = atomicAdd(&acc[bb2], 0.f);
                float ac = atomicAdd(&cnt[bb2], 0.f);
                loss += as / (ac * 3.0f);
            }
            out[0] = loss * (1.0f / BATCH);
        }
    }
}

extern "C" void kernel_launch(void* const* d_in, const int* in_sizes, int n_in,
                              void* d_out, int out_size, void* d_ws, size_t ws_size,
                              hipStream_t stream) {
    const float* src = (const float*)d_in[0];
    const float* tgt = (const float*)d_in[1];
    float* out = (float*)d_out;

    // ws: [0,16) acc[4]; [16,32) cnt[4]; [32,36) ticket; [4096, 4096+1M) packed B
    float* hdr = (float*)d_ws;
    float* acc = hdr;
    float* cnt = hdr + 4;
    unsigned* ticket = (unsigned*)((char*)d_ws + 32);
    short8* packed = (short8*)((char*)d_ws + 4096);  // 4*512*32*16 B = 1 MB

    knn_prep<<<dim3(256), 256, 0, stream>>>(tgt, packed, hdr);

    knn_main<<<dim3(128, 1, BATCH), 256, 0, stream>>>(src, packed, acc, cnt,
                                                      ticket, out);
}

// Round 8
// 147.326 us; speedup vs baseline: 1.1329x; 1.1329x over previous
//
#include <hip/hip_runtime.h>
#include <math.h>

// knnLoss B=4,N=8192,k=3: d^2 via one mfma_f32_32x32x16_bf16 per 32x32 tile
// (K=13 hi/lo-split embedding, r7-verified numerics), register-prefetch feed,
// in-block cross-wave merge (no partials buffer, no merge kernel).
// A slots k0-12 (per source): [mxh,mxh,mxl, myh,myh,myl, mzh,mzh | mzl, s2h,
//   s2l, 1, 1, 0,0,0]   (m* = -2*s)
// B slots k0-12 (per target): [txh,txl,txh, tyh,tyl,tyh, tzh,tzl | tzh, 1, 1,
//   t2h, t2l, 0,0,0]
// A[m][k]: m=lane&31, k=(lane>>5)*8+j ; B[k][n]: n=lane&31, k=(lane>>5)*8+j
// C[row][col]: col=lane&31, row=(reg&3)+8*(reg>>2)+4*(lane>>5)  [m74/m101]
#define BATCH 4
#define NPTS 8192
#define TILES_B 256          // 32-target tiles per batch
#define GROUPS 256           // 32-source groups per batch

typedef __attribute__((ext_vector_type(8))) short short8;
typedef __attribute__((ext_vector_type(16))) float floatx16;

__device__ __forceinline__ unsigned short bf16hi(float v) {
    unsigned u = __float_as_uint(v);
    return (unsigned short)((u + 0x7FFFu + ((u >> 16) & 1u)) >> 16);
}
__device__ __forceinline__ float bf16f(unsigned short h) {
    return __uint_as_float(((unsigned)h) << 16);
}

// Branchless insert into sorted ascending triple; 4 ops via med3.
__device__ __forceinline__ void insert3(float d, float& a0, float& a1, float& a2) {
    float h = fmaxf(a1, d);
    float m = __builtin_amdgcn_fmed3f(a0, a1, d);
    a2 = fminf(a2, h);
    a1 = m;
    a0 = fminf(a0, d);
}

// Merge sorted triple a into sorted triple b (3 smallest of union). 6 ops.
__device__ __forceinline__ void merge33(float a0, float a1, float a2,
                                        float& b0, float& b1, float& b2) {
    float s0 = fminf(a0, b0);
    float h  = fmaxf(a0, b0);
    float m  = fminf(a1, b1);
    float mm = fminf(a2, b2);
    b1 = fminf(h, m);
    b2 = __builtin_amdgcn_fmed3f(h, m, mm);
    b0 = s0;
}

// Pack B fragments: entry (b, tile, lane64) -> short8, 16 B. Total 4 MB/4 = 1 MB.
__global__ __launch_bounds__(256) void knn_prep(const float* __restrict__ tgt,
                                                short8* __restrict__ packed,
                                                float* __restrict__ hdr) {
    int gid = blockIdx.x * 256 + threadIdx.x;   // 0..65535
    if (gid < 16) hdr[gid] = 0.0f;              // zero acc/cnt/ticket header
    int lane = gid & 63;
    int bt = gid >> 6;                          // b*TILES_B + tile
    int n = lane & 31, h = lane >> 5;
    int b = bt >> 8, tile = bt & 255;
    const float* tp = tgt + ((size_t)b * NPTS + tile * 32 + n) * 3;
    float x = tp[0], y = tp[1], z = tp[2];
    float t2 = x * x + y * y + z * z;
    if (!(x != 0.f || y != 0.f || z != 0.f)) t2 = 3.0e38f;  // sentinel
    unsigned short xh = bf16hi(x),  xl = bf16hi(x - bf16f(xh));
    unsigned short yh = bf16hi(y),  yl = bf16hi(y - bf16f(yh));
    unsigned short zh = bf16hi(z),  zl = bf16hi(z - bf16f(zh));
    unsigned short th = bf16hi(t2), tl = bf16hi(t2 - bf16f(th));
    const short one = (short)0x3F80;
    short8 v;
    if (h == 0)
        v = (short8){(short)xh, (short)xl, (short)xh, (short)yh,
                     (short)yl, (short)yh, (short)zh, (short)zl};
    else
        v = (short8){(short)zh, one, one, (short)th, (short)tl, 0, 0, 0};
    packed[gid] = v;
}

// grid (GROUPS, BATCH), 256 threads = 4 waves; wave w: this group's 32 sources
// x target quarter [w*2048, w*2048+2048) = 64 tiles.
__global__ __launch_bounds__(256, 4) void knn_main(const float* __restrict__ src,
                                                   const short8* __restrict__ packed,
                                                   float* __restrict__ acc,
                                                   float* __restrict__ cnt,
                                                   unsigned* __restrict__ ticket,
                                                   float* __restrict__ out) {
    const int tid = threadIdx.x;
    const int wave = tid >> 6, lane = tid & 63;
    const int g = blockIdx.x, b = blockIdx.y;
    const int col = lane & 31, h = lane >> 5;

    // A fragment for source (g*32 + col), k-half h.
    const float* sp = src + ((size_t)b * NPTS + g * 32 + col) * 3;
    float sx = sp[0], sy = sp[1], sz = sp[2];
    float s2 = sx * sx + sy * sy + sz * sz;
    float mx = -2.f * sx, my = -2.f * sy, mz = -2.f * sz;
    unsigned short xh = bf16hi(mx), xl = bf16hi(mx - bf16f(xh));
    unsigned short yh = bf16hi(my), yl = bf16hi(my - bf16f(yh));
    unsigned short zh = bf16hi(mz), zl = bf16hi(mz - bf16f(zh));
    unsigned short sh = bf16hi(s2), sl = bf16hi(s2 - bf16f(sh));
    const short one = (short)0x3F80;
    short8 afrag;
    if (h == 0)
        afrag = (short8){(short)xh, (short)xh, (short)xl, (short)yh,
                         (short)yh, (short)yl, (short)zh, (short)zh};
    else
        afrag = (short8){(short)zl, (short)sh, (short)sl, one, one, 0, 0, 0};

    // 16 ascending-d^2 triples per lane (one per C reg / source row).
    float t0[16], t1[16], t2v[16];
    #pragma unroll
    for (int j = 0; j < 16; ++j) { t0[j] = t1[j] = t2v[j] = 3e38f; }

    // Depth-2 register-prefetch ring over this wave's 64 tiles.
    const short8* bb = packed + ((size_t)b * TILES_B + wave * 64) * 64 + lane;
    short8 f0 = bb[0];
    short8 f1 = bb[64];
    #pragma unroll 4
    for (int t = 0; t < 64; ++t) {
        int tn = t + 2 < 64 ? t + 2 : 63;
        short8 fn = bb[(size_t)tn * 64];        // issue load 2 tiles ahead
        floatx16 c = {};
        c = __builtin_amdgcn_mfma_f32_32x32x16_bf16(afrag, f0, c, 0, 0, 0);
        #pragma unroll
        for (int j = 0; j < 16; ++j) insert3(c[j], t0[j], t1[j], t2v[j]);
        f0 = f1;
        f1 = fn;
    }

    // Butterfly-merge across the 32 target-columns (masks stay within half).
    #pragma unroll
    for (int mask = 1; mask <= 16; mask <<= 1) {
        #pragma unroll
        for (int j = 0; j < 16; ++j) {
            float b0 = __shfl_xor(t0[j], mask);
            float b1 = __shfl_xor(t1[j], mask);
            float b2 = __shfl_xor(t2v[j], mask);
            merge33(b0, b1, b2, t0[j], t1[j], t2v[j]);
        }
    }

    // Lane (col==j) publishes row (j&3)+8*(j>>2)+4*h of this wave.
    __shared__ float red[4][32][3];
    #pragma unroll
    for (int j = 0; j < 16; ++j) {
        if (col == j) {
            int row = (j & 3) + 8 * (j >> 2) + 4 * h;
            red[wave][row][0] = t0[j];
            red[wave][row][1] = t1[j];
            red[wave][row][2] = t2v[j];
        }
    }
    __syncthreads();

    // Cross-wave merge (4 target-quarters), sqrt, validity, block reduce.
    float dsum = 0.f, dcnt = 0.f;
    if (tid < 32) {
        int row = tid;
        float m0 = red[0][row][0], m1 = red[0][row][1], m2 = red[0][row][2];
        merge33(red[1][row][0], red[1][row][1], red[1][row][2], m0, m1, m2);
        merge33(red[2][row][0], red[2][row][1], red[2][row][2], m0, m1, m2);
        merge33(red[3][row][0], red[3][row][1], red[3][row][2], m0, m1, m2);
        const float* vp = src + ((size_t)b * NPTS + g * 32 + row) * 3;
        float vx = vp[0], vy = vp[1], vz = vp[2];
        if (vx != 0.f || vy != 0.f || vz != 0.f) {
            dsum = sqrtf(fmaxf(m0, 0.f)) + sqrtf(fmaxf(m1, 0.f)) +
                   sqrtf(fmaxf(m2, 0.f));
            dcnt = 1.f;
        }
    }
    if (wave == 0) {
        for (int off = 16; off >= 1; off >>= 1) {
            dsum += __shfl_down(dsum, off);
            dcnt += __shfl_down(dcnt, off);
        }
    }
    if (tid == 0) {
        atomicAdd(&acc[b], dsum);
        atomicAdd(&cnt[b], dcnt);
        __threadfence();
        unsigned t = atomicAdd(ticket, 1u);
        if (t == (unsigned)(gridDim.x * gridDim.y - 1)) {
            float loss = 0.f;
            #pragma unroll
            for (int bb2 = 0; bb2 < BATCH; ++bb2) {
                float as = atomicAdd(&acc[bb2], 0.f);
                float ac = atomicAdd(&cnt[bb2], 0.f);
                loss += as / (ac * 3.0f);
            }
            out[0] = loss * (1.0f / BATCH);
        }
    }
}

extern "C" void kernel_launch(void* const* d_in, const int* in_sizes, int n_in,
                              void* d_out, int out_size, void* d_ws, size_t ws_size,
                              hipStream_t stream) {
    const float* src = (const float*)d_in[0];
    const float* tgt = (const float*)d_in[1];
    float* out = (float*)d_out;

    // ws: [0,16) acc[4]; [16,32) cnt[4]; [32,36) ticket; [4096, 4096+1M) packed B
    float* hdr = (float*)d_ws;
    float* acc = hdr;
    float* cnt = hdr + 4;
    unsigned* ticket = (unsigned*)((char*)d_ws + 32);
    short8* packed = (short8*)((char*)d_ws + 4096);  // 4*256*64*16 B = 1 MB

    knn_prep<<<dim3(256), 256, 0, stream>>>(tgt, packed, hdr);

    knn_main<<<dim3(GROUPS, BATCH), 256, 0, stream>>>(src, packed, acc, cnt,
                                                      ticket, out);
}